// Round 19
// baseline (106.549 us; speedup 1.0000x reference)
//
#include <hip/hip_runtime.h>
#include <math.h>

// SSIM loss, round 19: persistent 3-tile pipeline + fused finish.
//  - 2048 blocks x 3 tiles (32x64 each; math identical to validated r17).
//  - Cross-tile double-buffered LDS staging: loads for tile k+1 issued right
//    after tile k's barrier, written to the alternate buffer next iteration.
//    One barrier per tile (buffer reuse separated by two barriers).
//  - Fused deterministic finish: per-block partial -> threadfence ->
//    counter atomicAdd; LAST block re-reads partials via atomicAdd(p, 0.f)
//    (device-scope, XCD-coherent) and does a fixed-order double sum ->
//    out[0]. 4-byte hipMemsetAsync zeroes the counter each call.
//  - Removes the ssim_final dispatch (+dependency) from the timed graph.

typedef _Float16 f16x8 __attribute__((ext_vector_type(8)));
typedef _Float16 f16x4 __attribute__((ext_vector_type(4)));
typedef float f32x4 __attribute__((ext_vector_type(4)));
typedef _Float16 h2 __attribute__((ext_vector_type(2)));

#if __has_builtin(__builtin_amdgcn_mfma_f32_16x16x16_f16)
#define MFMA16 __builtin_amdgcn_mfma_f32_16x16x16_f16
#else
#define MFMA16 __builtin_amdgcn_mfma_f32_16x16x16f16
#endif

#define RAWP 88                  // f16 pitch of raw rows (80 data + 8 pad)
#define NPIX (16 * 3 * 512 * 512)
#define NBLK 2048                // persistent blocks
#define TILES 6144               // 48 planes * 16x8 tiles of 32x64

union U4 { f16x4 v; h2 p[2]; };
union U8 { f16x8 v; h2 p[4]; };
union UP { h2 h; unsigned u; };
union UB2 { unsigned u[2]; f16x4 v; };

static __device__ __forceinline__ h2 pkrtz(float a, float b) {
    auto r = __builtin_amdgcn_cvt_pkrtz(a, b);
    union { decltype(r) f; h2 h; } x; x.f = r; return x.h;
}
static __device__ __forceinline__ unsigned pk_u32(float a, float b) {
    UP x; x.h = pkrtz(a, b); return x.u;
}

// ---- compile-time band-fragment tables (validated r16/r17) -------------
struct alignas(16) BandTabs { float bh[64][8]; float wa0[64][4]; float wa16[64][4]; };
static constexpr BandTabs mk_tabs() {
    constexpr float GW[11] = {
        0.00102838f, 0.00759876f, 0.03600026f, 0.10936083f, 0.21300567f,
        0.26601190f, 0.21300567f, 0.10936083f, 0.03600026f, 0.00759876f,
        0.00102838f};
    BandTabs t{};
    for (int lane = 0; lane < 64; ++lane) {
        const int l15 = lane & 15, kg = lane >> 4;
        for (int j = 0; j < 8; ++j) {
            const int ib = (kg * 8 + j) - l15 - 3;
            t.bh[lane][j] = (ib >= 0 && ib < 11) ? GW[ib] : 0.0f;
        }
        for (int j = 0; j < 4; ++j) {
            const int kl = 4 * kg + j;
            const int i0 = kl - l15;
            const int i1 = 16 + kl - l15;
            t.wa0[lane][j]  = (i0 >= 0 && i0 < 11) ? GW[i0] : 0.0f;
            t.wa16[lane][j] = (i1 >= 0 && i1 < 11) ? GW[i1] : 0.0f;
        }
    }
    return t;
}
__device__ constexpr BandTabs TAB = mk_tabs();

static __device__ __forceinline__ f16x8 load_band8(const float* row) {
    const float4 a = *(const float4*)row;
    const float4 b = *(const float4*)(row + 4);
    U8 r;
    r.p[0] = pkrtz(a.x, a.y); r.p[1] = pkrtz(a.z, a.w);
    r.p[2] = pkrtz(b.x, b.y); r.p[3] = pkrtz(b.z, b.w);
    return r.v;
}
static __device__ __forceinline__ f16x4 load_band4(const float* row) {
    const float4 a = *(const float4*)row;
    U4 r;
    r.p[0] = pkrtz(a.x, a.y); r.p[1] = pkrtz(a.z, a.w);
    return r.v;
}

__global__ __launch_bounds__(256, 4) void ssim_fused(
    const float* __restrict__ X, const float* __restrict__ Y,
    float* __restrict__ partial, unsigned* __restrict__ counter,
    float* __restrict__ out)
{
    __shared__ _Float16 raw[2][2][48 * RAWP];   // 33,792 B (dbuf x {x,y})
    __shared__ float red[4];
    __shared__ int lastFlag;
    __shared__ double ws2[4];

    const int tid = threadIdx.x;
    const int bid = blockIdx.x;

    const int w    = tid >> 6;           // wave id = n-tile (out cols 16w..)
    const int lane = tid & 63;
    const int l15  = lane & 15;
    const int kg   = lane >> 4;

    // staging meta (48 rows x 20 quads = 960 units; <=4/thread)
    int ru_[4], c4_[4]; bool uok_[4];
#pragma unroll
    for (int i = 0; i < 4; ++i) {
        const int u = tid + 256 * i;
        ru_[i] = u / 20;
        c4_[i] = u - ru_[i] * 20;
        uok_[i] = (u < 960);
    }

    // band fragments from constant tables
    const f16x8 BH    = load_band8(TAB.bh[lane]);
    const f16x4 WVA0  = load_band4(TAB.wa0[lane]);
    const f16x4 WVA16 = load_band4(TAB.wa16[lane]);

    const f32x4 zero4 = {0.f, 0.f, 0.f, 0.f};
    const float4 f4z = make_float4(0.f, 0.f, 0.f, 0.f);
    const int rawc = 16 * w + 8 * kg;
    const float C1 = 0.0004f, C2 = 0.0036f;
    float lsum = 0.f;
    float4 px[4], py[4];

    // tile geometry + load-issue for pipeline stage k (compile-time k)
    auto issue = [&](int k) {
        const int g   = k * NBLK + bid;
        const int wgk = (g & 7) * (TILES / 8) + (g >> 3);   // XCD swizzle
        const int pl  = wgk >> 7;          // 128 tiles per plane
        const int tt  = wgk & 127;
        const int tr  = tt >> 3;           // 0..15
        const int tc  = tt & 7;            // 0..7
        const float* xp = X + (size_t)pl * (512 * 512);
        const float* yp = Y + (size_t)pl * (512 * 512);
        const int row0 = tr * 32 - 5;
        const int colB = tc * 64 - 8;
#pragma unroll
        for (int i = 0; i < 4; ++i) {
            const int gr = row0 + ru_[i];
            const int gc = colB + 4 * c4_[i];
            const bool ok = uok_[i] && ((unsigned)gr < 512u) && ((unsigned)gc <= 508u);
            px[i] = ok ? *(const float4*)(xp + gr * 512 + gc) : f4z;
            py[i] = ok ? *(const float4*)(yp + gr * 512 + gc) : f4z;
        }
    };

    issue(0);                              // prologue

#pragma unroll
    for (int k = 0; k < 3; ++k) {
        const int buf = k & 1;
        // ---- write staged regs -> LDS[buf] ----
        _Float16* rx = raw[buf][0];
        _Float16* ry = raw[buf][1];
#pragma unroll
        for (int i = 0; i < 4; ++i) {
            if (uok_[i]) {
                const int off = ru_[i] * RAWP + 4 * c4_[i];
                U4 tx, ty;
                tx.p[0] = pkrtz(px[i].x, px[i].y); tx.p[1] = pkrtz(px[i].z, px[i].w);
                ty.p[0] = pkrtz(py[i].x, py[i].y); ty.p[1] = pkrtz(py[i].z, py[i].w);
                *(f16x4*)(rx + off) = tx.v;
                *(f16x4*)(ry + off) = ty.v;
            }
        }
        __syncthreads();                   // LDS[buf] ready (1 barrier/tile)

        if (k < 2) issue(k + 1);           // overlap next tile's loads

        // ---- Phase A: h-blur MFMA -> packed C in regs ----
        unsigned pq[4][3][2];
#pragma unroll
        for (int mt = 0; mt < 3; ++mt) {
            const int r = mt * 16 + l15;
            const f16x8 fx = *(const f16x8*)(rx + r * RAWP + rawc);
            const f16x8 fy = *(const f16x8*)(ry + r * RAWP + rawc);
            const f16x8 fxy = fx * fy;
            const f16x8 fss = fx * fx + fy * fy;

            const f32x4 c0 = __builtin_amdgcn_mfma_f32_16x16x32_f16(fx,  BH, zero4, 0, 0, 0);
            const f32x4 c1 = __builtin_amdgcn_mfma_f32_16x16x32_f16(fy,  BH, zero4, 0, 0, 0);
            const f32x4 c2 = __builtin_amdgcn_mfma_f32_16x16x32_f16(fss, BH, zero4, 0, 0, 0);
            const f32x4 c3 = __builtin_amdgcn_mfma_f32_16x16x32_f16(fxy, BH, zero4, 0, 0, 0);

            pq[0][mt][0] = pk_u32(c0[0], c0[1]); pq[0][mt][1] = pk_u32(c0[2], c0[3]);
            pq[1][mt][0] = pk_u32(c1[0], c1[1]); pq[1][mt][1] = pk_u32(c1[2], c1[3]);
            pq[2][mt][0] = pk_u32(c2[0], c2[1]); pq[2][mt][1] = pk_u32(c2[2], c2[3]);
            pq[3][mt][0] = pk_u32(c3[0], c3[1]); pq[3][mt][1] = pk_u32(c3[2], c3[3]);
        }

        // ---- Phase C: v-blur K=16 MFMAs in place + epilogue ----
#pragma unroll
        for (int mtv = 0; mtv < 2; ++mtv) {
            f32x4 v[4];
#pragma unroll
            for (int q = 0; q < 4; ++q) {
                UB2 blo, bhi;
                blo.u[0] = pq[q][mtv][0];     blo.u[1] = pq[q][mtv][1];
                bhi.u[0] = pq[q][mtv + 1][0]; bhi.u[1] = pq[q][mtv + 1][1];
                f32x4 acc = MFMA16(WVA16, bhi.v, zero4, 0, 0, 0);
                v[q] = MFMA16(WVA0, blo.v, acc, 0, 0, 0);
            }
#pragma unroll
            for (int r2 = 0; r2 < 4; ++r2) {
                const float mux = v[0][r2], muy = v[1][r2];
                const float ess = v[2][r2], exy = v[3][r2];
                const float mux2 = mux * mux, muy2 = muy * muy, muxy = mux * muy;
                const float svar = fmaxf(ess - mux2 - muy2, 0.f);
                const float sxy = exy - muxy;
                const float num = (2.f * muxy + C1) * (2.f * sxy + C2);
                const float den = (mux2 + muy2 + C1) * (svar + C2);
                lsum += num * __builtin_amdgcn_rcpf(den);
            }
        }
    }

    // ---- block reduction -> partial, then fused deterministic finish ----
#pragma unroll
    for (int off = 32; off > 0; off >>= 1)
        lsum += __shfl_down(lsum, off, 64);
    if (lane == 0) red[w] = lsum;
    __syncthreads();
    if (tid == 0) {
        partial[bid] = red[0] + red[1] + red[2] + red[3];
        __threadfence();                   // partial visible device-wide
        const unsigned old = atomicAdd(counter, 1u);
        lastFlag = (old == NBLK - 1);
    }
    __syncthreads();

    if (lastFlag) {
        // last block: fixed-order double sum of all partials (deterministic
        // regardless of which block runs it). atomicAdd(p, 0.f) reads are
        // device-scope -> coherent across XCDs.
        double s = 0.0;
#pragma unroll
        for (int j = 0; j < 8; ++j)
            s += (double)atomicAdd(&partial[tid * 8 + j], 0.0f);
#pragma unroll
        for (int off = 32; off > 0; off >>= 1)
            s += __shfl_down(s, off, 64);
        if (lane == 0) ws2[w] = s;
        __syncthreads();
        if (tid == 0) {
            const double tot = ws2[0] + ws2[1] + ws2[2] + ws2[3];
            out[0] = (float)(1.0 - tot / (double)NPIX);
        }
    }
}

extern "C" void kernel_launch(void* const* d_in, const int* in_sizes, int n_in,
                              void* d_out, int out_size, void* d_ws, size_t ws_size,
                              hipStream_t stream)
{
    const float* x = (const float*)d_in[0];   // pred
    const float* y = (const float*)d_in[1];   // target
    float* partial = (float*)d_ws;            // NBLK*4 = 8,192 B
    unsigned* counter = (unsigned*)((char*)d_ws + NBLK * 4);
    float* out = (float*)d_out;

    hipMemsetAsync(counter, 0, sizeof(unsigned), stream);
    ssim_fused<<<NBLK, 256, 0, stream>>>(x, y, partial, counter, out);
}